// Round 10
// baseline (123.272 us; speedup 1.0000x reference)
//
#include <hip/hip_runtime.h>

#define HH 1024
#define WW 1024
#define NB 4
#define RR 8
#define NCH1 13
#define NCH2 4
#define VSEG 8
#define NSEG (HH / VSEG)          // 128 row-segments per batch
#define TW 512                    // column-tile width
#define NWS (WW / TW)             // 2 tiles across
#define NBLK (NB * NSEG * NWS)    // 1024 blocks
#define NXCD 8
#define CPX (NBLK / NXCD)         // 128 logical blocks per XCD = one strip
#define LDSW 544                  // 8 halo + 512 + 8 halo + 16 pad
#define INV_AREA (1.0f/289.0f)
#define EPS_REG 0.01f

typedef float f2 __attribute__((ext_vector_type(2)));
typedef _Float16 h2 __attribute__((ext_vector_type(2)));

__device__ __forceinline__ int refl(int j, int n) {
    int k = j < 0 ? -j : j;
    return k >= n ? 2 * n - 2 - k : k;
}

// XCD swizzle: hw round-robins blocks over 8 XCDs; remap so XCD x owns
// logical [x*128,(x+1)*128) = one full (batch, col-half) strip, rows in order
// => vertical warm-up overlap dedups in that XCD's private L2.
__device__ __forceinline__ int swz_logical(int id) {
    return (id & (NXCD - 1)) * CPX + (id >> 3);
}

__device__ __forceinline__ void derived13(f2 i0, f2 i1, f2 i2, f2 pp, f2* d) {
    d[0] = i0; d[1] = i1; d[2] = i2; d[3] = pp;
    d[4] = i0 * pp; d[5] = i1 * pp; d[6] = i2 * pp;
    d[7] = i0 * i0; d[8] = i0 * i1; d[9] = i0 * i2;
    d[10] = i1 * i1; d[11] = i1 * i2; d[12] = i2 * i2;
}

__device__ __forceinline__ void derived13s(float i0, float i1, float i2, float pp, float* d) {
    d[0] = i0; d[1] = i1; d[2] = i2; d[3] = pp;
    d[4] = i0 * pp; d[5] = i1 * pp; d[6] = i2 * pp;
    d[7] = i0 * i0; d[8] = i0 * i1; d[9] = i0 * i2;
    d[10] = i1 * i1; d[11] = i1 * i2; d[12] = i2 * i2;
}

// horizontal 17-tap for 2 owned cols; window for tile-col k is lds pos k..k+16
__device__ __forceinline__ f2 hwin(const float* ldsrow, int c0) {
    const f2* wp = (const f2*)(ldsrow + c0);
    f2 w0 = wp[0], w1 = wp[1], w2 = wp[2], w3 = wp[3];
    f2 w4 = wp[4], w5 = wp[5], w6 = wp[6], w7 = wp[7], w8 = wp[8];
    f2 e = ((w0 + w1) + (w2 + w3)) + ((w4 + w5) + (w6 + w7));
    float s0 = e[0] + e[1] + w8[0];
    float s1 = s0 - w0[0] + w8[1];
    f2 r; r[0] = s0 * INV_AREA; r[1] = s1 * INV_AREA;
    return r;
}

// Stage 1: 256 thr, 2 cols/thread over a 512-col tile + 16-col halo state in
// threads 0..15. VSEG=8 vertical sliding sums, 28KB LDS, 3x3 solve, fp16 a,b.
__global__ __launch_bounds__(256, 4) void gf_stage1(
    const float* __restrict__ I, const float* __restrict__ P,
    _Float16* __restrict__ A, _Float16* __restrict__ Bc)
{
    __shared__ float lds[NCH1][LDSW];
    const int tid = threadIdx.x;
    const int logical = swz_logical(blockIdx.x);
    const int strip = logical / NSEG;           // 0..7: (bz, whalf)
    const int y0 = (logical % NSEG) * VSEG;
    const int bz = strip >> 1;
    const int wstart = (strip & 1) * TW;
    const int c0 = 2 * tid;                     // tile-local col
    const int gc = wstart + c0;                 // global col
    const float* Ib = I + (size_t)bz * 3 * HH * WW;
    const float* Pb = P + (size_t)bz * HH * WW;

    // halo: threads 0..7 left cols wstart-8+tid, 8..15 right cols wstart+TW+(tid-8)
    const bool isHalo = tid < 16;
    const int hraw = (tid < 8) ? (wstart - 8 + tid) : (wstart + TW + (tid - 8));
    const int hg = refl(hraw, WW);
    const int hpos = (tid < 8) ? tid : (8 + TW + (tid - 8));

    f2 vs[NCH1];
    float hs[NCH1];
    #pragma unroll
    for (int ch = 0; ch < NCH1; ++ch) { vs[ch] = (f2){0.f, 0.f}; hs[ch] = 0.f; }

    // warm-up rows y0-8 .. y0+8 (reflected)
    for (int dy = -RR; dy <= RR; ++dy) {
        int row = refl(y0 + dy, HH);
        size_t rb = (size_t)row * WW;
        f2 i0 = *(const f2*)(Ib + rb + gc);
        f2 i1 = *(const f2*)(Ib + (size_t)HH * WW + rb + gc);
        f2 i2 = *(const f2*)(Ib + (size_t)2 * HH * WW + rb + gc);
        f2 pp = *(const f2*)(Pb + rb + gc);
        f2 d[NCH1]; derived13(i0, i1, i2, pp, d);
        #pragma unroll
        for (int ch = 0; ch < NCH1; ++ch) vs[ch] += d[ch];
        if (isHalo) {
            float j0 = Ib[rb + hg];
            float j1 = Ib[(size_t)HH * WW + rb + hg];
            float j2 = Ib[(size_t)2 * HH * WW + rb + hg];
            float jp = Pb[rb + hg];
            float ds[NCH1]; derived13s(j0, j1, j2, jp, ds);
            #pragma unroll
            for (int ch = 0; ch < NCH1; ++ch) hs[ch] += ds[ch];
        }
    }

    for (int y = y0; y < y0 + VSEG; ++y) {
        #pragma unroll
        for (int ch = 0; ch < NCH1; ++ch)
            *(f2*)&lds[ch][8 + c0] = vs[ch];
        if (isHalo) {
            #pragma unroll
            for (int ch = 0; ch < NCH1; ++ch) lds[ch][hpos] = hs[ch];
        }
        // prefetch next add/sub rows (in flight across the barrier)
        const bool upd = (y + 1 < y0 + VSEG);
        f2 ai0, ai1, ai2, ap, si0, si1, si2, sp;
        float hai0, hai1, hai2, hap, hsi0, hsi1, hsi2, hsp;
        if (upd) {
            int ra = refl(y + 1 + RR, HH);
            int rs = refl(y - RR, HH);
            size_t rba = (size_t)ra * WW;
            size_t rbs = (size_t)rs * WW;
            ai0 = *(const f2*)(Ib + rba + gc);
            ai1 = *(const f2*)(Ib + (size_t)HH * WW + rba + gc);
            ai2 = *(const f2*)(Ib + (size_t)2 * HH * WW + rba + gc);
            ap  = *(const f2*)(Pb + rba + gc);
            si0 = *(const f2*)(Ib + rbs + gc);
            si1 = *(const f2*)(Ib + (size_t)HH * WW + rbs + gc);
            si2 = *(const f2*)(Ib + (size_t)2 * HH * WW + rbs + gc);
            sp  = *(const f2*)(Pb + rbs + gc);
            if (isHalo) {
                hai0 = Ib[rba + hg];
                hai1 = Ib[(size_t)HH * WW + rba + hg];
                hai2 = Ib[(size_t)2 * HH * WW + rba + hg];
                hap  = Pb[rba + hg];
                hsi0 = Ib[rbs + hg];
                hsi1 = Ib[(size_t)HH * WW + rbs + hg];
                hsi2 = Ib[(size_t)2 * HH * WW + rbs + hg];
                hsp  = Pb[rbs + hg];
            }
        }
        __syncthreads();

        f2 m[NCH1];
        #pragma unroll
        for (int ch = 0; ch < NCH1; ++ch)
            m[ch] = hwin(&lds[ch][0], c0);

        // per-pixel 3x3 symmetric solve (adjugate)
        f2 oa0, oa1, oa2, ob;
        #pragma unroll
        for (int j = 0; j < 2; ++j) {
            float m0 = m[0][j], m1 = m[1][j], m2 = m[2][j], m3 = m[3][j];
            float r0 = m[4][j] - m0 * m3;
            float r1 = m[5][j] - m1 * m3;
            float r2 = m[6][j] - m2 * m3;
            float S00 = m[7][j]  - m0 * m0 + EPS_REG;
            float S01 = m[8][j]  - m0 * m1;
            float S02 = m[9][j]  - m0 * m2;
            float S11 = m[10][j] - m1 * m1 + EPS_REG;
            float S12 = m[11][j] - m1 * m2;
            float S22 = m[12][j] - m2 * m2 + EPS_REG;
            float A0 = S11 * S22 - S12 * S12;
            float B0 = S02 * S12 - S01 * S22;
            float C0 = S01 * S12 - S02 * S11;
            float D0 = S00 * S22 - S02 * S02;
            float E0 = S01 * S02 - S00 * S12;
            float F0 = S00 * S11 - S01 * S01;
            float det = S00 * A0 + S01 * B0 + S02 * C0;
            float inv = 1.0f / det;
            float a0 = (A0 * r0 + B0 * r1 + C0 * r2) * inv;
            float a1 = (B0 * r0 + D0 * r1 + E0 * r2) * inv;
            float a2 = (C0 * r0 + E0 * r1 + F0 * r2) * inv;
            float bb = m3 - (a0 * m0 + a1 * m1 + a2 * m2);
            oa0[j] = a0; oa1[j] = a1; oa2[j] = a2; ob[j] = bb;
        }
        size_t obase = (size_t)y * WW + gc;
        *(h2*)(A + (size_t)(bz * 3 + 0) * HH * WW + obase) = __builtin_convertvector(oa0, h2);
        *(h2*)(A + (size_t)(bz * 3 + 1) * HH * WW + obase) = __builtin_convertvector(oa1, h2);
        *(h2*)(A + (size_t)(bz * 3 + 2) * HH * WW + obase) = __builtin_convertvector(oa2, h2);
        *(h2*)(Bc + (size_t)bz * HH * WW + obase) = __builtin_convertvector(ob, h2);
        __syncthreads();

        if (upd) {
            f2 d[NCH1];
            derived13(ai0, ai1, ai2, ap, d);
            #pragma unroll
            for (int ch = 0; ch < NCH1; ++ch) vs[ch] += d[ch];
            derived13(si0, si1, si2, sp, d);
            #pragma unroll
            for (int ch = 0; ch < NCH1; ++ch) vs[ch] -= d[ch];
            if (isHalo) {
                float ds[NCH1];
                derived13s(hai0, hai1, hai2, hap, ds);
                #pragma unroll
                for (int ch = 0; ch < NCH1; ++ch) hs[ch] += ds[ch];
                derived13s(hsi0, hsi1, hsi2, hsp, ds);
                #pragma unroll
                for (int ch = 0; ch < NCH1; ++ch) hs[ch] -= ds[ch];
            }
        }
    }
}

// Stage 2: box filter a(3),b(1) (fp16 in) with same tiling; q out f32.
__global__ __launch_bounds__(256, 4) void gf_stage2(
    const float* __restrict__ I, const _Float16* __restrict__ A,
    const _Float16* __restrict__ Bc, float* __restrict__ Q)
{
    __shared__ float lds[NCH2][LDSW];
    const int tid = threadIdx.x;
    const int logical = swz_logical(blockIdx.x);
    const int strip = logical / NSEG;
    const int y0 = (logical % NSEG) * VSEG;
    const int bz = strip >> 1;
    const int wstart = (strip & 1) * TW;
    const int c0 = 2 * tid;
    const int gc = wstart + c0;
    const _Float16* A0p = A + (size_t)(bz * 3 + 0) * HH * WW;
    const _Float16* A1p = A + (size_t)(bz * 3 + 1) * HH * WW;
    const _Float16* A2p = A + (size_t)(bz * 3 + 2) * HH * WW;
    const _Float16* Bp  = Bc + (size_t)bz * HH * WW;
    const float* Ib  = I + (size_t)bz * 3 * HH * WW;

    const bool isHalo = tid < 16;
    const int hraw = (tid < 8) ? (wstart - 8 + tid) : (wstart + TW + (tid - 8));
    const int hg = refl(hraw, WW);
    const int hpos = (tid < 8) ? tid : (8 + TW + (tid - 8));

    f2 vs[NCH2];
    float hs[NCH2];
    #pragma unroll
    for (int ch = 0; ch < NCH2; ++ch) { vs[ch] = (f2){0.f, 0.f}; hs[ch] = 0.f; }

    for (int dy = -RR; dy <= RR; ++dy) {
        int row = refl(y0 + dy, HH);
        size_t rb = (size_t)row * WW;
        vs[0] += __builtin_convertvector(*(const h2*)(A0p + rb + gc), f2);
        vs[1] += __builtin_convertvector(*(const h2*)(A1p + rb + gc), f2);
        vs[2] += __builtin_convertvector(*(const h2*)(A2p + rb + gc), f2);
        vs[3] += __builtin_convertvector(*(const h2*)(Bp + rb + gc), f2);
        if (isHalo) {
            hs[0] += (float)A0p[rb + hg];
            hs[1] += (float)A1p[rb + hg];
            hs[2] += (float)A2p[rb + hg];
            hs[3] += (float)Bp[rb + hg];
        }
    }

    for (int y = y0; y < y0 + VSEG; ++y) {
        #pragma unroll
        for (int ch = 0; ch < NCH2; ++ch)
            *(f2*)&lds[ch][8 + c0] = vs[ch];
        if (isHalo) {
            #pragma unroll
            for (int ch = 0; ch < NCH2; ++ch) lds[ch][hpos] = hs[ch];
        }
        const bool upd = (y + 1 < y0 + VSEG);
        f2 aa0, aa1, aa2, ab, sa0, sa1, sa2, sb;
        float ha0, ha1, ha2, hab, hb0, hb1, hb2, hbb;
        size_t rbq = (size_t)y * WW;
        f2 i0 = *(const f2*)(Ib + rbq + gc);
        f2 i1 = *(const f2*)(Ib + (size_t)HH * WW + rbq + gc);
        f2 i2 = *(const f2*)(Ib + (size_t)2 * HH * WW + rbq + gc);
        if (upd) {
            int ra = refl(y + 1 + RR, HH);
            int rs = refl(y - RR, HH);
            size_t rba = (size_t)ra * WW;
            size_t rbs = (size_t)rs * WW;
            aa0 = __builtin_convertvector(*(const h2*)(A0p + rba + gc), f2);
            aa1 = __builtin_convertvector(*(const h2*)(A1p + rba + gc), f2);
            aa2 = __builtin_convertvector(*(const h2*)(A2p + rba + gc), f2);
            ab  = __builtin_convertvector(*(const h2*)(Bp + rba + gc), f2);
            sa0 = __builtin_convertvector(*(const h2*)(A0p + rbs + gc), f2);
            sa1 = __builtin_convertvector(*(const h2*)(A1p + rbs + gc), f2);
            sa2 = __builtin_convertvector(*(const h2*)(A2p + rbs + gc), f2);
            sb  = __builtin_convertvector(*(const h2*)(Bp + rbs + gc), f2);
            if (isHalo) {
                ha0 = (float)A0p[rba + hg]; ha1 = (float)A1p[rba + hg];
                ha2 = (float)A2p[rba + hg]; hab = (float)Bp[rba + hg];
                hb0 = (float)A0p[rbs + hg]; hb1 = (float)A1p[rbs + hg];
                hb2 = (float)A2p[rbs + hg]; hbb = (float)Bp[rbs + hg];
            }
        }
        __syncthreads();

        f2 m[NCH2];
        #pragma unroll
        for (int ch = 0; ch < NCH2; ++ch)
            m[ch] = hwin(&lds[ch][0], c0);

        f2 qv = m[0] * i0 + m[1] * i1 + m[2] * i2 + m[3];
        *(f2*)(Q + (size_t)bz * HH * WW + rbq + gc) = qv;
        __syncthreads();

        if (upd) {
            vs[0] += aa0 - sa0;
            vs[1] += aa1 - sa1;
            vs[2] += aa2 - sa2;
            vs[3] += ab - sb;
            if (isHalo) {
                hs[0] += ha0 - hb0; hs[1] += ha1 - hb1;
                hs[2] += ha2 - hb2; hs[3] += hab - hbb;
            }
        }
    }
}

extern "C" void kernel_launch(void* const* d_in, const int* in_sizes, int n_in,
                              void* d_out, int out_size, void* d_ws, size_t ws_size,
                              hipStream_t stream) {
    const float* I = (const float*)d_in[0];
    const float* P = (const float*)d_in[1];
    float* Q = (float*)d_out;
    _Float16* A = (_Float16*)d_ws;                       // B*3*H*W halves
    _Float16* Bc = A + (size_t)NB * 3 * HH * WW;         // B*H*W halves
    gf_stage1<<<NBLK, 256, 0, stream>>>(I, P, A, Bc);
    gf_stage2<<<NBLK, 256, 0, stream>>>(I, A, Bc, Q);
}

// Round 11
// 106.245 us; speedup vs baseline: 1.1603x; 1.1603x over previous
//
#include <hip/hip_runtime.h>

#define HH 1024
#define WW 1024
#define NB 4
#define RR 8
#define NCH1 13
#define NCH2 4
#define VSEG 8
#define NSEG (HH / VSEG)          // 128 row-segments per batch
#define TW 512                    // column-tile width
#define NWS (WW / TW)             // 2 tiles across
#define NBLK (NB * NSEG * NWS)    // 1024 blocks
#define NXCD 8
#define CPX (NBLK / NXCD)         // 128 logical blocks per XCD = one strip
#define LDSW 544                  // 8 halo + 512 + 8 halo + 16 pad
#define INV_AREA (1.0f/289.0f)
#define EPS_REG 0.01f

typedef float f2 __attribute__((ext_vector_type(2)));
typedef _Float16 h2 __attribute__((ext_vector_type(2)));

__device__ __forceinline__ int refl(int j, int n) {
    int k = j < 0 ? -j : j;
    return k >= n ? 2 * n - 2 - k : k;
}

// XCD swizzle: hw round-robins blocks over 8 XCDs; remap so XCD x owns
// logical [x*128,(x+1)*128) = one full (batch, col-half) strip, rows in order
// => vertical warm-up overlap dedups in that XCD's private L2.
__device__ __forceinline__ int swz_logical(int id) {
    return (id & (NXCD - 1)) * CPX + (id >> 3);
}

__device__ __forceinline__ void derived13(f2 i0, f2 i1, f2 i2, f2 pp, f2* d) {
    d[0] = i0; d[1] = i1; d[2] = i2; d[3] = pp;
    d[4] = i0 * pp; d[5] = i1 * pp; d[6] = i2 * pp;
    d[7] = i0 * i0; d[8] = i0 * i1; d[9] = i0 * i2;
    d[10] = i1 * i1; d[11] = i1 * i2; d[12] = i2 * i2;
}

__device__ __forceinline__ void derived13s(float i0, float i1, float i2, float pp, float* d) {
    d[0] = i0; d[1] = i1; d[2] = i2; d[3] = pp;
    d[4] = i0 * pp; d[5] = i1 * pp; d[6] = i2 * pp;
    d[7] = i0 * i0; d[8] = i0 * i1; d[9] = i0 * i2;
    d[10] = i1 * i1; d[11] = i1 * i2; d[12] = i2 * i2;
}

// horizontal 17-tap for 2 owned cols; window for tile-col k is lds pos k..k+16
__device__ __forceinline__ f2 hwin(const float* ldsrow, int c0) {
    const f2* wp = (const f2*)(ldsrow + c0);
    f2 w0 = wp[0], w1 = wp[1], w2 = wp[2], w3 = wp[3];
    f2 w4 = wp[4], w5 = wp[5], w6 = wp[6], w7 = wp[7], w8 = wp[8];
    f2 e = ((w0 + w1) + (w2 + w3)) + ((w4 + w5) + (w6 + w7));
    float s0 = e[0] + e[1] + w8[0];
    float s1 = s0 - w0[0] + w8[1];
    f2 r; r[0] = s0 * INV_AREA; r[1] = s1 * INV_AREA;
    return r;
}

// Stage 1: 256 thr, 2 cols/thread over a 512-col tile + 16-col halo state in
// threads 0..15. VSEG=8 vertical sliding sums, 28KB LDS, 3x3 solve, fp16 a,b.
// launch_bounds(256,2) ONLY: any 2nd arg >=3 on this toolchain forces a
// 64-72 VGPR cap and spills (rounds 3/6/10). Natural use ~110-125 -> 4
// blocks/CU by LDS (4x28KB) and 4 waves/SIMD by VGPR (<=128), no spill.
__global__ __launch_bounds__(256, 2) void gf_stage1(
    const float* __restrict__ I, const float* __restrict__ P,
    _Float16* __restrict__ A, _Float16* __restrict__ Bc)
{
    __shared__ float lds[NCH1][LDSW];
    const int tid = threadIdx.x;
    const int logical = swz_logical(blockIdx.x);
    const int strip = logical / NSEG;           // 0..7: (bz, whalf)
    const int y0 = (logical % NSEG) * VSEG;
    const int bz = strip >> 1;
    const int wstart = (strip & 1) * TW;
    const int c0 = 2 * tid;                     // tile-local col
    const int gc = wstart + c0;                 // global col
    const float* Ib = I + (size_t)bz * 3 * HH * WW;
    const float* Pb = P + (size_t)bz * HH * WW;

    // halo: threads 0..7 left cols wstart-8+tid, 8..15 right cols wstart+TW+(tid-8)
    const bool isHalo = tid < 16;
    const int hraw = (tid < 8) ? (wstart - 8 + tid) : (wstart + TW + (tid - 8));
    const int hg = refl(hraw, WW);
    const int hpos = (tid < 8) ? tid : (8 + TW + (tid - 8));

    f2 vs[NCH1];
    float hs[NCH1];
    #pragma unroll
    for (int ch = 0; ch < NCH1; ++ch) { vs[ch] = (f2){0.f, 0.f}; hs[ch] = 0.f; }

    // warm-up rows y0-8 .. y0+8 (reflected)
    for (int dy = -RR; dy <= RR; ++dy) {
        int row = refl(y0 + dy, HH);
        size_t rb = (size_t)row * WW;
        f2 i0 = *(const f2*)(Ib + rb + gc);
        f2 i1 = *(const f2*)(Ib + (size_t)HH * WW + rb + gc);
        f2 i2 = *(const f2*)(Ib + (size_t)2 * HH * WW + rb + gc);
        f2 pp = *(const f2*)(Pb + rb + gc);
        f2 d[NCH1]; derived13(i0, i1, i2, pp, d);
        #pragma unroll
        for (int ch = 0; ch < NCH1; ++ch) vs[ch] += d[ch];
        if (isHalo) {
            float j0 = Ib[rb + hg];
            float j1 = Ib[(size_t)HH * WW + rb + hg];
            float j2 = Ib[(size_t)2 * HH * WW + rb + hg];
            float jp = Pb[rb + hg];
            float ds[NCH1]; derived13s(j0, j1, j2, jp, ds);
            #pragma unroll
            for (int ch = 0; ch < NCH1; ++ch) hs[ch] += ds[ch];
        }
    }

    for (int y = y0; y < y0 + VSEG; ++y) {
        #pragma unroll
        for (int ch = 0; ch < NCH1; ++ch)
            *(f2*)&lds[ch][8 + c0] = vs[ch];
        if (isHalo) {
            #pragma unroll
            for (int ch = 0; ch < NCH1; ++ch) lds[ch][hpos] = hs[ch];
        }
        // prefetch next add/sub rows (in flight across the barrier)
        const bool upd = (y + 1 < y0 + VSEG);
        f2 ai0, ai1, ai2, ap, si0, si1, si2, sp;
        float hai0, hai1, hai2, hap, hsi0, hsi1, hsi2, hsp;
        if (upd) {
            int ra = refl(y + 1 + RR, HH);
            int rs = refl(y - RR, HH);
            size_t rba = (size_t)ra * WW;
            size_t rbs = (size_t)rs * WW;
            ai0 = *(const f2*)(Ib + rba + gc);
            ai1 = *(const f2*)(Ib + (size_t)HH * WW + rba + gc);
            ai2 = *(const f2*)(Ib + (size_t)2 * HH * WW + rba + gc);
            ap  = *(const f2*)(Pb + rba + gc);
            si0 = *(const f2*)(Ib + rbs + gc);
            si1 = *(const f2*)(Ib + (size_t)HH * WW + rbs + gc);
            si2 = *(const f2*)(Ib + (size_t)2 * HH * WW + rbs + gc);
            sp  = *(const f2*)(Pb + rbs + gc);
            if (isHalo) {
                hai0 = Ib[rba + hg];
                hai1 = Ib[(size_t)HH * WW + rba + hg];
                hai2 = Ib[(size_t)2 * HH * WW + rba + hg];
                hap  = Pb[rba + hg];
                hsi0 = Ib[rbs + hg];
                hsi1 = Ib[(size_t)HH * WW + rbs + hg];
                hsi2 = Ib[(size_t)2 * HH * WW + rbs + hg];
                hsp  = Pb[rbs + hg];
            }
        }
        __syncthreads();

        f2 m[NCH1];
        #pragma unroll
        for (int ch = 0; ch < NCH1; ++ch)
            m[ch] = hwin(&lds[ch][0], c0);

        // per-pixel 3x3 symmetric solve (adjugate)
        f2 oa0, oa1, oa2, ob;
        #pragma unroll
        for (int j = 0; j < 2; ++j) {
            float m0 = m[0][j], m1 = m[1][j], m2 = m[2][j], m3 = m[3][j];
            float r0 = m[4][j] - m0 * m3;
            float r1 = m[5][j] - m1 * m3;
            float r2 = m[6][j] - m2 * m3;
            float S00 = m[7][j]  - m0 * m0 + EPS_REG;
            float S01 = m[8][j]  - m0 * m1;
            float S02 = m[9][j]  - m0 * m2;
            float S11 = m[10][j] - m1 * m1 + EPS_REG;
            float S12 = m[11][j] - m1 * m2;
            float S22 = m[12][j] - m2 * m2 + EPS_REG;
            float A0 = S11 * S22 - S12 * S12;
            float B0 = S02 * S12 - S01 * S22;
            float C0 = S01 * S12 - S02 * S11;
            float D0 = S00 * S22 - S02 * S02;
            float E0 = S01 * S02 - S00 * S12;
            float F0 = S00 * S11 - S01 * S01;
            float det = S00 * A0 + S01 * B0 + S02 * C0;
            float inv = 1.0f / det;
            float a0 = (A0 * r0 + B0 * r1 + C0 * r2) * inv;
            float a1 = (B0 * r0 + D0 * r1 + E0 * r2) * inv;
            float a2 = (C0 * r0 + E0 * r1 + F0 * r2) * inv;
            float bb = m3 - (a0 * m0 + a1 * m1 + a2 * m2);
            oa0[j] = a0; oa1[j] = a1; oa2[j] = a2; ob[j] = bb;
        }
        size_t obase = (size_t)y * WW + gc;
        *(h2*)(A + (size_t)(bz * 3 + 0) * HH * WW + obase) = __builtin_convertvector(oa0, h2);
        *(h2*)(A + (size_t)(bz * 3 + 1) * HH * WW + obase) = __builtin_convertvector(oa1, h2);
        *(h2*)(A + (size_t)(bz * 3 + 2) * HH * WW + obase) = __builtin_convertvector(oa2, h2);
        *(h2*)(Bc + (size_t)bz * HH * WW + obase) = __builtin_convertvector(ob, h2);
        __syncthreads();

        if (upd) {
            f2 d[NCH1];
            derived13(ai0, ai1, ai2, ap, d);
            #pragma unroll
            for (int ch = 0; ch < NCH1; ++ch) vs[ch] += d[ch];
            derived13(si0, si1, si2, sp, d);
            #pragma unroll
            for (int ch = 0; ch < NCH1; ++ch) vs[ch] -= d[ch];
            if (isHalo) {
                float ds[NCH1];
                derived13s(hai0, hai1, hai2, hap, ds);
                #pragma unroll
                for (int ch = 0; ch < NCH1; ++ch) hs[ch] += ds[ch];
                derived13s(hsi0, hsi1, hsi2, hsp, ds);
                #pragma unroll
                for (int ch = 0; ch < NCH1; ++ch) hs[ch] -= ds[ch];
            }
        }
    }
}

// Stage 2: box filter a(3),b(1) (fp16 in) with same tiling; q out f32.
__global__ __launch_bounds__(256, 2) void gf_stage2(
    const float* __restrict__ I, const _Float16* __restrict__ A,
    const _Float16* __restrict__ Bc, float* __restrict__ Q)
{
    __shared__ float lds[NCH2][LDSW];
    const int tid = threadIdx.x;
    const int logical = swz_logical(blockIdx.x);
    const int strip = logical / NSEG;
    const int y0 = (logical % NSEG) * VSEG;
    const int bz = strip >> 1;
    const int wstart = (strip & 1) * TW;
    const int c0 = 2 * tid;
    const int gc = wstart + c0;
    const _Float16* A0p = A + (size_t)(bz * 3 + 0) * HH * WW;
    const _Float16* A1p = A + (size_t)(bz * 3 + 1) * HH * WW;
    const _Float16* A2p = A + (size_t)(bz * 3 + 2) * HH * WW;
    const _Float16* Bp  = Bc + (size_t)bz * HH * WW;
    const float* Ib  = I + (size_t)bz * 3 * HH * WW;

    const bool isHalo = tid < 16;
    const int hraw = (tid < 8) ? (wstart - 8 + tid) : (wstart + TW + (tid - 8));
    const int hg = refl(hraw, WW);
    const int hpos = (tid < 8) ? tid : (8 + TW + (tid - 8));

    f2 vs[NCH2];
    float hs[NCH2];
    #pragma unroll
    for (int ch = 0; ch < NCH2; ++ch) { vs[ch] = (f2){0.f, 0.f}; hs[ch] = 0.f; }

    for (int dy = -RR; dy <= RR; ++dy) {
        int row = refl(y0 + dy, HH);
        size_t rb = (size_t)row * WW;
        vs[0] += __builtin_convertvector(*(const h2*)(A0p + rb + gc), f2);
        vs[1] += __builtin_convertvector(*(const h2*)(A1p + rb + gc), f2);
        vs[2] += __builtin_convertvector(*(const h2*)(A2p + rb + gc), f2);
        vs[3] += __builtin_convertvector(*(const h2*)(Bp + rb + gc), f2);
        if (isHalo) {
            hs[0] += (float)A0p[rb + hg];
            hs[1] += (float)A1p[rb + hg];
            hs[2] += (float)A2p[rb + hg];
            hs[3] += (float)Bp[rb + hg];
        }
    }

    for (int y = y0; y < y0 + VSEG; ++y) {
        #pragma unroll
        for (int ch = 0; ch < NCH2; ++ch)
            *(f2*)&lds[ch][8 + c0] = vs[ch];
        if (isHalo) {
            #pragma unroll
            for (int ch = 0; ch < NCH2; ++ch) lds[ch][hpos] = hs[ch];
        }
        const bool upd = (y + 1 < y0 + VSEG);
        f2 aa0, aa1, aa2, ab, sa0, sa1, sa2, sb;
        float ha0, ha1, ha2, hab, hb0, hb1, hb2, hbb;
        size_t rbq = (size_t)y * WW;
        f2 i0 = *(const f2*)(Ib + rbq + gc);
        f2 i1 = *(const f2*)(Ib + (size_t)HH * WW + rbq + gc);
        f2 i2 = *(const f2*)(Ib + (size_t)2 * HH * WW + rbq + gc);
        if (upd) {
            int ra = refl(y + 1 + RR, HH);
            int rs = refl(y - RR, HH);
            size_t rba = (size_t)ra * WW;
            size_t rbs = (size_t)rs * WW;
            aa0 = __builtin_convertvector(*(const h2*)(A0p + rba + gc), f2);
            aa1 = __builtin_convertvector(*(const h2*)(A1p + rba + gc), f2);
            aa2 = __builtin_convertvector(*(const h2*)(A2p + rba + gc), f2);
            ab  = __builtin_convertvector(*(const h2*)(Bp + rba + gc), f2);
            sa0 = __builtin_convertvector(*(const h2*)(A0p + rbs + gc), f2);
            sa1 = __builtin_convertvector(*(const h2*)(A1p + rbs + gc), f2);
            sa2 = __builtin_convertvector(*(const h2*)(A2p + rbs + gc), f2);
            sb  = __builtin_convertvector(*(const h2*)(Bp + rbs + gc), f2);
            if (isHalo) {
                ha0 = (float)A0p[rba + hg]; ha1 = (float)A1p[rba + hg];
                ha2 = (float)A2p[rba + hg]; hab = (float)Bp[rba + hg];
                hb0 = (float)A0p[rbs + hg]; hb1 = (float)A1p[rbs + hg];
                hb2 = (float)A2p[rbs + hg]; hbb = (float)Bp[rbs + hg];
            }
        }
        __syncthreads();

        f2 m[NCH2];
        #pragma unroll
        for (int ch = 0; ch < NCH2; ++ch)
            m[ch] = hwin(&lds[ch][0], c0);

        f2 qv = m[0] * i0 + m[1] * i1 + m[2] * i2 + m[3];
        *(f2*)(Q + (size_t)bz * HH * WW + rbq + gc) = qv;
        __syncthreads();

        if (upd) {
            vs[0] += aa0 - sa0;
            vs[1] += aa1 - sa1;
            vs[2] += aa2 - sa2;
            vs[3] += ab - sb;
            if (isHalo) {
                hs[0] += ha0 - hb0; hs[1] += ha1 - hb1;
                hs[2] += ha2 - hb2; hs[3] += hab - hbb;
            }
        }
    }
}

extern "C" void kernel_launch(void* const* d_in, const int* in_sizes, int n_in,
                              void* d_out, int out_size, void* d_ws, size_t ws_size,
                              hipStream_t stream) {
    const float* I = (const float*)d_in[0];
    const float* P = (const float*)d_in[1];
    float* Q = (float*)d_out;
    _Float16* A = (_Float16*)d_ws;                       // B*3*H*W halves
    _Float16* Bc = A + (size_t)NB * 3 * HH * WW;         // B*H*W halves
    gf_stage1<<<NBLK, 256, 0, stream>>>(I, P, A, Bc);
    gf_stage2<<<NBLK, 256, 0, stream>>>(I, A, Bc, Q);
}

// Round 12
// 86.625 us; speedup vs baseline: 1.4231x; 1.2265x over previous
//
#include <hip/hip_runtime.h>

#define HH 1024
#define WW 1024
#define NB 4
#define RR 8
#define NCH1 13
#define NCH2 4
#define VSEG 8
#define NSEG (HH / VSEG)           // 128 row-segments per batch
#define NXCD 8
// stage1: full-width blocks
#define NBLK1 (NB * NSEG)          // 512
#define CPX1 (NBLK1 / NXCD)        // 64
#define LDSW1 1040                 // 8 pad + 1024 + 8 pad
// stage2: 512-col tiles
#define TW 512
#define NWS (WW / TW)              // 2
#define NBLK2 (NB * NSEG * NWS)    // 1024
#define CPX2 (NBLK2 / NXCD)        // 128
#define LDSW2 544                  // 8 halo + 512 + 8 halo + 16 pad
#define INV_AREA (1.0f/289.0f)
#define EPS_REG 0.01f

typedef float f4 __attribute__((ext_vector_type(4)));
typedef _Float16 h4 __attribute__((ext_vector_type(4)));
typedef float f2 __attribute__((ext_vector_type(2)));
typedef _Float16 h2 __attribute__((ext_vector_type(2)));

__device__ __forceinline__ int refl(int j, int n) {
    int k = j < 0 ? -j : j;
    return k >= n ? 2 * n - 2 - k : k;
}

__device__ __forceinline__ void derived13(f4 i0, f4 i1, f4 i2, f4 pp, f4* d) {
    d[0] = i0; d[1] = i1; d[2] = i2; d[3] = pp;
    d[4] = i0 * pp; d[5] = i1 * pp; d[6] = i2 * pp;
    d[7] = i0 * i0; d[8] = i0 * i1; d[9] = i0 * i2;
    d[10] = i1 * i1; d[11] = i1 * i2; d[12] = i2 * i2;
}

// ---------------- Stage 1: round-8 config (proven 57 us) ----------------
// 256 thr, 4 cols/thread full width, VSEG=8, 54KB LDS, fp16 a,b out,
// XCD swizzle (each XCD gets 64 consecutive row-segments).
__global__ __launch_bounds__(256, 2) void gf_stage1(
    const float* __restrict__ I, const float* __restrict__ P,
    _Float16* __restrict__ A, _Float16* __restrict__ Bc)
{
    __shared__ float lds[NCH1][LDSW1];
    const int tid = threadIdx.x;
    const int logical = (blockIdx.x & (NXCD - 1)) * CPX1 + (blockIdx.x >> 3);
    const int bz = logical / NSEG;
    const int y0 = (logical % NSEG) * VSEG;
    const int c0 = 4 * tid;
    const float* Ib = I + (size_t)bz * 3 * HH * WW;
    const float* Pb = P + (size_t)bz * HH * WW;

    f4 vs[NCH1];
    #pragma unroll
    for (int ch = 0; ch < NCH1; ++ch) { vs[ch] = (f4){0.f, 0.f, 0.f, 0.f}; }

    for (int dy = -RR; dy <= RR; ++dy) {
        int row = refl(y0 + dy, HH);
        size_t rb = (size_t)row * WW + c0;
        f4 i0 = *(const f4*)(Ib + rb);
        f4 i1 = *(const f4*)(Ib + (size_t)HH * WW + rb);
        f4 i2 = *(const f4*)(Ib + (size_t)2 * HH * WW + rb);
        f4 pp = *(const f4*)(Pb + rb);
        f4 d[NCH1]; derived13(i0, i1, i2, pp, d);
        #pragma unroll
        for (int ch = 0; ch < NCH1; ++ch) vs[ch] += d[ch];
    }

    for (int y = y0; y < y0 + VSEG; ++y) {
        #pragma unroll
        for (int ch = 0; ch < NCH1; ++ch)
            *(f4*)&lds[ch][8 + c0] = vs[ch];
        if (tid <= 2) {
            #pragma unroll
            for (int j = 0; j < 4; ++j) {
                int c = c0 + j;
                if (c >= 1 && c <= 8) {
                    #pragma unroll
                    for (int ch = 0; ch < NCH1; ++ch) lds[ch][8 - c] = vs[ch][j];
                }
            }
        }
        if (tid >= 253) {
            #pragma unroll
            for (int j = 0; j < 4; ++j) {
                int c = c0 + j;
                if (c >= 1015 && c <= 1022) {
                    #pragma unroll
                    for (int ch = 0; ch < NCH1; ++ch) lds[ch][1032 + (1022 - c)] = vs[ch][j];
                }
            }
        }
        const bool upd = (y + 1 < y0 + VSEG);
        f4 ai0, ai1, ai2, ap, si0, si1, si2, sp;
        if (upd) {
            int ra = refl(y + 1 + RR, HH);
            int rs = refl(y - RR, HH);
            size_t rba = (size_t)ra * WW + c0;
            size_t rbs = (size_t)rs * WW + c0;
            ai0 = *(const f4*)(Ib + rba);
            ai1 = *(const f4*)(Ib + (size_t)HH * WW + rba);
            ai2 = *(const f4*)(Ib + (size_t)2 * HH * WW + rba);
            ap  = *(const f4*)(Pb + rba);
            si0 = *(const f4*)(Ib + rbs);
            si1 = *(const f4*)(Ib + (size_t)HH * WW + rbs);
            si2 = *(const f4*)(Ib + (size_t)2 * HH * WW + rbs);
            sp  = *(const f4*)(Pb + rbs);
        }
        __syncthreads();

        f4 m[NCH1];
        #pragma unroll
        for (int ch = 0; ch < NCH1; ++ch) {
            float vv[20];
            #pragma unroll
            for (int k = 0; k < 5; ++k)
                ((f4*)vv)[k] = *(const f4*)&lds[ch][c0 + 4 * k];
            float s = (((vv[0]+vv[1])+(vv[2]+vv[3])) + ((vv[4]+vv[5])+(vv[6]+vv[7])))
                    + (((vv[8]+vv[9])+(vv[10]+vv[11])) + ((vv[12]+vv[13])+(vv[14]+vv[15])))
                    + vv[16];
            f4 mm;
            mm[0] = s;
            s += vv[17] - vv[0]; mm[1] = s;
            s += vv[18] - vv[1]; mm[2] = s;
            s += vv[19] - vv[2]; mm[3] = s;
            m[ch] = mm * INV_AREA;
        }

        f4 oa0, oa1, oa2, ob;
        #pragma unroll
        for (int j = 0; j < 4; ++j) {
            float m0 = m[0][j], m1 = m[1][j], m2 = m[2][j], m3 = m[3][j];
            float r0 = m[4][j] - m0 * m3;
            float r1 = m[5][j] - m1 * m3;
            float r2 = m[6][j] - m2 * m3;
            float S00 = m[7][j]  - m0 * m0 + EPS_REG;
            float S01 = m[8][j]  - m0 * m1;
            float S02 = m[9][j]  - m0 * m2;
            float S11 = m[10][j] - m1 * m1 + EPS_REG;
            float S12 = m[11][j] - m1 * m2;
            float S22 = m[12][j] - m2 * m2 + EPS_REG;
            float A0 = S11 * S22 - S12 * S12;
            float B0 = S02 * S12 - S01 * S22;
            float C0 = S01 * S12 - S02 * S11;
            float D0 = S00 * S22 - S02 * S02;
            float E0 = S01 * S02 - S00 * S12;
            float F0 = S00 * S11 - S01 * S01;
            float det = S00 * A0 + S01 * B0 + S02 * C0;
            float inv = 1.0f / det;
            float a0 = (A0 * r0 + B0 * r1 + C0 * r2) * inv;
            float a1 = (B0 * r0 + D0 * r1 + E0 * r2) * inv;
            float a2 = (C0 * r0 + E0 * r1 + F0 * r2) * inv;
            float bb = m3 - (a0 * m0 + a1 * m1 + a2 * m2);
            oa0[j] = a0; oa1[j] = a1; oa2[j] = a2; ob[j] = bb;
        }
        size_t obase = (size_t)y * WW + c0;
        *(h4*)(A + (size_t)(bz * 3 + 0) * HH * WW + obase) = __builtin_convertvector(oa0, h4);
        *(h4*)(A + (size_t)(bz * 3 + 1) * HH * WW + obase) = __builtin_convertvector(oa1, h4);
        *(h4*)(A + (size_t)(bz * 3 + 2) * HH * WW + obase) = __builtin_convertvector(oa2, h4);
        *(h4*)(Bc + (size_t)bz * HH * WW + obase) = __builtin_convertvector(ob, h4);
        __syncthreads();

        if (upd) {
            f4 d[NCH1];
            derived13(ai0, ai1, ai2, ap, d);
            #pragma unroll
            for (int ch = 0; ch < NCH1; ++ch) vs[ch] += d[ch];
            derived13(si0, si1, si2, sp, d);
            #pragma unroll
            for (int ch = 0; ch < NCH1; ++ch) vs[ch] -= d[ch];
        }
    }
}

// ---------------- Stage 2: round-11 config (proven ~17 us) ----------------
// 256 thr, 2 cols/thread over 512-col tile + 16-col halo in threads 0..15.
__device__ __forceinline__ f2 hwin2(const float* ldsrow, int c0) {
    const f2* wp = (const f2*)(ldsrow + c0);
    f2 w0 = wp[0], w1 = wp[1], w2 = wp[2], w3 = wp[3];
    f2 w4 = wp[4], w5 = wp[5], w6 = wp[6], w7 = wp[7], w8 = wp[8];
    f2 e = ((w0 + w1) + (w2 + w3)) + ((w4 + w5) + (w6 + w7));
    float s0 = e[0] + e[1] + w8[0];
    float s1 = s0 - w0[0] + w8[1];
    f2 r; r[0] = s0 * INV_AREA; r[1] = s1 * INV_AREA;
    return r;
}

__global__ __launch_bounds__(256, 2) void gf_stage2(
    const float* __restrict__ I, const _Float16* __restrict__ A,
    const _Float16* __restrict__ Bc, float* __restrict__ Q)
{
    __shared__ float lds[NCH2][LDSW2];
    const int tid = threadIdx.x;
    const int logical = (blockIdx.x & (NXCD - 1)) * CPX2 + (blockIdx.x >> 3);
    const int strip = logical / NSEG;
    const int y0 = (logical % NSEG) * VSEG;
    const int bz = strip >> 1;
    const int wstart = (strip & 1) * TW;
    const int c0 = 2 * tid;
    const int gc = wstart + c0;
    const _Float16* A0p = A + (size_t)(bz * 3 + 0) * HH * WW;
    const _Float16* A1p = A + (size_t)(bz * 3 + 1) * HH * WW;
    const _Float16* A2p = A + (size_t)(bz * 3 + 2) * HH * WW;
    const _Float16* Bp  = Bc + (size_t)bz * HH * WW;
    const float* Ib  = I + (size_t)bz * 3 * HH * WW;

    const bool isHalo = tid < 16;
    const int hraw = (tid < 8) ? (wstart - 8 + tid) : (wstart + TW + (tid - 8));
    const int hg = refl(hraw, WW);
    const int hpos = (tid < 8) ? tid : (8 + TW + (tid - 8));

    f2 vs[NCH2];
    float hs[NCH2];
    #pragma unroll
    for (int ch = 0; ch < NCH2; ++ch) { vs[ch] = (f2){0.f, 0.f}; hs[ch] = 0.f; }

    for (int dy = -RR; dy <= RR; ++dy) {
        int row = refl(y0 + dy, HH);
        size_t rb = (size_t)row * WW;
        vs[0] += __builtin_convertvector(*(const h2*)(A0p + rb + gc), f2);
        vs[1] += __builtin_convertvector(*(const h2*)(A1p + rb + gc), f2);
        vs[2] += __builtin_convertvector(*(const h2*)(A2p + rb + gc), f2);
        vs[3] += __builtin_convertvector(*(const h2*)(Bp + rb + gc), f2);
        if (isHalo) {
            hs[0] += (float)A0p[rb + hg];
            hs[1] += (float)A1p[rb + hg];
            hs[2] += (float)A2p[rb + hg];
            hs[3] += (float)Bp[rb + hg];
        }
    }

    for (int y = y0; y < y0 + VSEG; ++y) {
        #pragma unroll
        for (int ch = 0; ch < NCH2; ++ch)
            *(f2*)&lds[ch][8 + c0] = vs[ch];
        if (isHalo) {
            #pragma unroll
            for (int ch = 0; ch < NCH2; ++ch) lds[ch][hpos] = hs[ch];
        }
        const bool upd = (y + 1 < y0 + VSEG);
        f2 aa0, aa1, aa2, ab, sa0, sa1, sa2, sb;
        float ha0, ha1, ha2, hab, hb0, hb1, hb2, hbb;
        size_t rbq = (size_t)y * WW;
        f2 i0 = *(const f2*)(Ib + rbq + gc);
        f2 i1 = *(const f2*)(Ib + (size_t)HH * WW + rbq + gc);
        f2 i2 = *(const f2*)(Ib + (size_t)2 * HH * WW + rbq + gc);
        if (upd) {
            int ra = refl(y + 1 + RR, HH);
            int rs = refl(y - RR, HH);
            size_t rba = (size_t)ra * WW;
            size_t rbs = (size_t)rs * WW;
            aa0 = __builtin_convertvector(*(const h2*)(A0p + rba + gc), f2);
            aa1 = __builtin_convertvector(*(const h2*)(A1p + rba + gc), f2);
            aa2 = __builtin_convertvector(*(const h2*)(A2p + rba + gc), f2);
            ab  = __builtin_convertvector(*(const h2*)(Bp + rba + gc), f2);
            sa0 = __builtin_convertvector(*(const h2*)(A0p + rbs + gc), f2);
            sa1 = __builtin_convertvector(*(const h2*)(A1p + rbs + gc), f2);
            sa2 = __builtin_convertvector(*(const h2*)(A2p + rbs + gc), f2);
            sb  = __builtin_convertvector(*(const h2*)(Bp + rbs + gc), f2);
            if (isHalo) {
                ha0 = (float)A0p[rba + hg]; ha1 = (float)A1p[rba + hg];
                ha2 = (float)A2p[rba + hg]; hab = (float)Bp[rba + hg];
                hb0 = (float)A0p[rbs + hg]; hb1 = (float)A1p[rbs + hg];
                hb2 = (float)A2p[rbs + hg]; hbb = (float)Bp[rbs + hg];
            }
        }
        __syncthreads();

        f2 m[NCH2];
        #pragma unroll
        for (int ch = 0; ch < NCH2; ++ch)
            m[ch] = hwin2(&lds[ch][0], c0);

        f2 qv = m[0] * i0 + m[1] * i1 + m[2] * i2 + m[3];
        *(f2*)(Q + (size_t)bz * HH * WW + rbq + gc) = qv;
        __syncthreads();

        if (upd) {
            vs[0] += aa0 - sa0;
            vs[1] += aa1 - sa1;
            vs[2] += aa2 - sa2;
            vs[3] += ab - sb;
            if (isHalo) {
                hs[0] += ha0 - hb0; hs[1] += ha1 - hb1;
                hs[2] += ha2 - hb2; hs[3] += hab - hbb;
            }
        }
    }
}

extern "C" void kernel_launch(void* const* d_in, const int* in_sizes, int n_in,
                              void* d_out, int out_size, void* d_ws, size_t ws_size,
                              hipStream_t stream) {
    const float* I = (const float*)d_in[0];
    const float* P = (const float*)d_in[1];
    float* Q = (float*)d_out;
    _Float16* A = (_Float16*)d_ws;                       // B*3*H*W halves
    _Float16* Bc = A + (size_t)NB * 3 * HH * WW;         // B*H*W halves
    gf_stage1<<<NBLK1, 256, 0, stream>>>(I, P, A, Bc);
    gf_stage2<<<NBLK2, 256, 0, stream>>>(I, A, Bc, Q);
}

// Round 13
// 81.319 us; speedup vs baseline: 1.5159x; 1.0652x over previous
//
#include <hip/hip_runtime.h>

#define HH 1024
#define WW 1024
#define NB 4
#define RR 8
#define NCH1 13
#define NCH2 4
#define NXCD 8
// stage1: full-width blocks, VSEG1=4 -> 1024 blocks (3 resident/CU by LDS)
#define VSEG1 4
#define NSEG1 (HH / VSEG1)         // 256 row-segments per batch
#define NBLK1 (NB * NSEG1)         // 1024
#define LDSW1 1040                 // 8 pad + 1024 + 8 pad
// stage2: 512-col tiles, VSEG2=8 -> 1024 blocks
#define VSEG2 8
#define NSEG2 (HH / VSEG2)         // 128
#define TW 512
#define NBLK2 (NB * NSEG2 * 2)     // 1024
#define LDSW2 544                  // 8 halo + 512 + 8 halo + 16 pad
#define INV_AREA (1.0f/289.0f)
#define EPS_REG 0.01f

typedef float f4 __attribute__((ext_vector_type(4)));
typedef _Float16 h4 __attribute__((ext_vector_type(4)));
typedef float f2 __attribute__((ext_vector_type(2)));
typedef _Float16 h2 __attribute__((ext_vector_type(2)));

__device__ __forceinline__ int refl(int j, int n) {
    int k = j < 0 ? -j : j;
    return k >= n ? 2 * n - 2 - k : k;
}

__device__ __forceinline__ void derived13(f4 i0, f4 i1, f4 i2, f4 pp, f4* d) {
    d[0] = i0; d[1] = i1; d[2] = i2; d[3] = pp;
    d[4] = i0 * pp; d[5] = i1 * pp; d[6] = i2 * pp;
    d[7] = i0 * i0; d[8] = i0 * i1; d[9] = i0 * i2;
    d[10] = i1 * i1; d[11] = i1 * i2; d[12] = i2 * i2;
}

// Both stages use the SAME XCD->pixel ownership: XCD x owns batch x>>1,
// row-half x&1, rows in consecutive order (warm-up overlap dedups in the
// private L2, and stage2 reads a,b from the XCD that wrote them).

// ---------------- Stage 1 ----------------
// 256 thr, 4 cols/thread full width, VSEG1=4, 54KB LDS (3 blocks/CU),
// fp16 a,b out. Same inner structure as round-12 (84 VGPR, spill-free).
__global__ __launch_bounds__(256, 2) void gf_stage1(
    const float* __restrict__ I, const float* __restrict__ P,
    _Float16* __restrict__ A, _Float16* __restrict__ Bc)
{
    __shared__ float lds[NCH1][LDSW1];
    const int tid = threadIdx.x;
    const int xcd = blockIdx.x & (NXCD - 1);
    const int rank = blockIdx.x >> 3;           // 0..127
    const int bz = xcd >> 1;
    const int seg = (xcd & 1) * 128 + rank;     // 0..255
    const int y0 = seg * VSEG1;
    const int c0 = 4 * tid;
    const float* Ib = I + (size_t)bz * 3 * HH * WW;
    const float* Pb = P + (size_t)bz * HH * WW;

    f4 vs[NCH1];
    #pragma unroll
    for (int ch = 0; ch < NCH1; ++ch) { vs[ch] = (f4){0.f, 0.f, 0.f, 0.f}; }

    for (int dy = -RR; dy <= RR; ++dy) {
        int row = refl(y0 + dy, HH);
        size_t rb = (size_t)row * WW + c0;
        f4 i0 = *(const f4*)(Ib + rb);
        f4 i1 = *(const f4*)(Ib + (size_t)HH * WW + rb);
        f4 i2 = *(const f4*)(Ib + (size_t)2 * HH * WW + rb);
        f4 pp = *(const f4*)(Pb + rb);
        f4 d[NCH1]; derived13(i0, i1, i2, pp, d);
        #pragma unroll
        for (int ch = 0; ch < NCH1; ++ch) vs[ch] += d[ch];
    }

    for (int y = y0; y < y0 + VSEG1; ++y) {
        #pragma unroll
        for (int ch = 0; ch < NCH1; ++ch)
            *(f4*)&lds[ch][8 + c0] = vs[ch];
        if (tid <= 2) {
            #pragma unroll
            for (int j = 0; j < 4; ++j) {
                int c = c0 + j;
                if (c >= 1 && c <= 8) {
                    #pragma unroll
                    for (int ch = 0; ch < NCH1; ++ch) lds[ch][8 - c] = vs[ch][j];
                }
            }
        }
        if (tid >= 253) {
            #pragma unroll
            for (int j = 0; j < 4; ++j) {
                int c = c0 + j;
                if (c >= 1015 && c <= 1022) {
                    #pragma unroll
                    for (int ch = 0; ch < NCH1; ++ch) lds[ch][1032 + (1022 - c)] = vs[ch][j];
                }
            }
        }
        const bool upd = (y + 1 < y0 + VSEG1);
        f4 ai0, ai1, ai2, ap, si0, si1, si2, sp;
        if (upd) {
            int ra = refl(y + 1 + RR, HH);
            int rs = refl(y - RR, HH);
            size_t rba = (size_t)ra * WW + c0;
            size_t rbs = (size_t)rs * WW + c0;
            ai0 = *(const f4*)(Ib + rba);
            ai1 = *(const f4*)(Ib + (size_t)HH * WW + rba);
            ai2 = *(const f4*)(Ib + (size_t)2 * HH * WW + rba);
            ap  = *(const f4*)(Pb + rba);
            si0 = *(const f4*)(Ib + rbs);
            si1 = *(const f4*)(Ib + (size_t)HH * WW + rbs);
            si2 = *(const f4*)(Ib + (size_t)2 * HH * WW + rbs);
            sp  = *(const f4*)(Pb + rbs);
        }
        __syncthreads();

        f4 m[NCH1];
        #pragma unroll
        for (int ch = 0; ch < NCH1; ++ch) {
            float vv[20];
            #pragma unroll
            for (int k = 0; k < 5; ++k)
                ((f4*)vv)[k] = *(const f4*)&lds[ch][c0 + 4 * k];
            float s = (((vv[0]+vv[1])+(vv[2]+vv[3])) + ((vv[4]+vv[5])+(vv[6]+vv[7])))
                    + (((vv[8]+vv[9])+(vv[10]+vv[11])) + ((vv[12]+vv[13])+(vv[14]+vv[15])))
                    + vv[16];
            f4 mm;
            mm[0] = s;
            s += vv[17] - vv[0]; mm[1] = s;
            s += vv[18] - vv[1]; mm[2] = s;
            s += vv[19] - vv[2]; mm[3] = s;
            m[ch] = mm * INV_AREA;
        }

        f4 oa0, oa1, oa2, ob;
        #pragma unroll
        for (int j = 0; j < 4; ++j) {
            float m0 = m[0][j], m1 = m[1][j], m2 = m[2][j], m3 = m[3][j];
            float r0 = m[4][j] - m0 * m3;
            float r1 = m[5][j] - m1 * m3;
            float r2 = m[6][j] - m2 * m3;
            float S00 = m[7][j]  - m0 * m0 + EPS_REG;
            float S01 = m[8][j]  - m0 * m1;
            float S02 = m[9][j]  - m0 * m2;
            float S11 = m[10][j] - m1 * m1 + EPS_REG;
            float S12 = m[11][j] - m1 * m2;
            float S22 = m[12][j] - m2 * m2 + EPS_REG;
            float A0 = S11 * S22 - S12 * S12;
            float B0 = S02 * S12 - S01 * S22;
            float C0 = S01 * S12 - S02 * S11;
            float D0 = S00 * S22 - S02 * S02;
            float E0 = S01 * S02 - S00 * S12;
            float F0 = S00 * S11 - S01 * S01;
            float det = S00 * A0 + S01 * B0 + S02 * C0;
            float inv = 1.0f / det;
            float a0 = (A0 * r0 + B0 * r1 + C0 * r2) * inv;
            float a1 = (B0 * r0 + D0 * r1 + E0 * r2) * inv;
            float a2 = (C0 * r0 + E0 * r1 + F0 * r2) * inv;
            float bb = m3 - (a0 * m0 + a1 * m1 + a2 * m2);
            oa0[j] = a0; oa1[j] = a1; oa2[j] = a2; ob[j] = bb;
        }
        size_t obase = (size_t)y * WW + c0;
        *(h4*)(A + (size_t)(bz * 3 + 0) * HH * WW + obase) = __builtin_convertvector(oa0, h4);
        *(h4*)(A + (size_t)(bz * 3 + 1) * HH * WW + obase) = __builtin_convertvector(oa1, h4);
        *(h4*)(A + (size_t)(bz * 3 + 2) * HH * WW + obase) = __builtin_convertvector(oa2, h4);
        *(h4*)(Bc + (size_t)bz * HH * WW + obase) = __builtin_convertvector(ob, h4);
        __syncthreads();

        if (upd) {
            f4 d[NCH1];
            derived13(ai0, ai1, ai2, ap, d);
            #pragma unroll
            for (int ch = 0; ch < NCH1; ++ch) vs[ch] += d[ch];
            derived13(si0, si1, si2, sp, d);
            #pragma unroll
            for (int ch = 0; ch < NCH1; ++ch) vs[ch] -= d[ch];
        }
    }
}

// ---------------- Stage 2 ----------------
// 256 thr, 2 cols/thread over 512-col tile + 16-col halo in threads 0..15.
// Mapping aligned with stage1: XCD x = (batch x>>1, row-half x&1).
__device__ __forceinline__ f2 hwin2(const float* ldsrow, int c0) {
    const f2* wp = (const f2*)(ldsrow + c0);
    f2 w0 = wp[0], w1 = wp[1], w2 = wp[2], w3 = wp[3];
    f2 w4 = wp[4], w5 = wp[5], w6 = wp[6], w7 = wp[7], w8 = wp[8];
    f2 e = ((w0 + w1) + (w2 + w3)) + ((w4 + w5) + (w6 + w7));
    float s0 = e[0] + e[1] + w8[0];
    float s1 = s0 - w0[0] + w8[1];
    f2 r; r[0] = s0 * INV_AREA; r[1] = s1 * INV_AREA;
    return r;
}

__global__ __launch_bounds__(256, 2) void gf_stage2(
    const float* __restrict__ I, const _Float16* __restrict__ A,
    const _Float16* __restrict__ Bc, float* __restrict__ Q)
{
    __shared__ float lds[NCH2][LDSW2];
    const int tid = threadIdx.x;
    const int xcd = blockIdx.x & (NXCD - 1);
    const int rank = blockIdx.x >> 3;                 // 0..127
    const int bz = xcd >> 1;
    const int seg = (xcd & 1) * 64 + (rank >> 1);     // 0..127
    const int y0 = seg * VSEG2;
    const int wstart = (rank & 1) * TW;
    const int c0 = 2 * tid;
    const int gc = wstart + c0;
    const _Float16* A0p = A + (size_t)(bz * 3 + 0) * HH * WW;
    const _Float16* A1p = A + (size_t)(bz * 3 + 1) * HH * WW;
    const _Float16* A2p = A + (size_t)(bz * 3 + 2) * HH * WW;
    const _Float16* Bp  = Bc + (size_t)bz * HH * WW;
    const float* Ib  = I + (size_t)bz * 3 * HH * WW;

    const bool isHalo = tid < 16;
    const int hraw = (tid < 8) ? (wstart - 8 + tid) : (wstart + TW + (tid - 8));
    const int hg = refl(hraw, WW);
    const int hpos = (tid < 8) ? tid : (8 + TW + (tid - 8));

    f2 vs[NCH2];
    float hs[NCH2];
    #pragma unroll
    for (int ch = 0; ch < NCH2; ++ch) { vs[ch] = (f2){0.f, 0.f}; hs[ch] = 0.f; }

    for (int dy = -RR; dy <= RR; ++dy) {
        int row = refl(y0 + dy, HH);
        size_t rb = (size_t)row * WW;
        vs[0] += __builtin_convertvector(*(const h2*)(A0p + rb + gc), f2);
        vs[1] += __builtin_convertvector(*(const h2*)(A1p + rb + gc), f2);
        vs[2] += __builtin_convertvector(*(const h2*)(A2p + rb + gc), f2);
        vs[3] += __builtin_convertvector(*(const h2*)(Bp + rb + gc), f2);
        if (isHalo) {
            hs[0] += (float)A0p[rb + hg];
            hs[1] += (float)A1p[rb + hg];
            hs[2] += (float)A2p[rb + hg];
            hs[3] += (float)Bp[rb + hg];
        }
    }

    for (int y = y0; y < y0 + VSEG2; ++y) {
        #pragma unroll
        for (int ch = 0; ch < NCH2; ++ch)
            *(f2*)&lds[ch][8 + c0] = vs[ch];
        if (isHalo) {
            #pragma unroll
            for (int ch = 0; ch < NCH2; ++ch) lds[ch][hpos] = hs[ch];
        }
        const bool upd = (y + 1 < y0 + VSEG2);
        f2 aa0, aa1, aa2, ab, sa0, sa1, sa2, sb;
        float ha0, ha1, ha2, hab, hb0, hb1, hb2, hbb;
        size_t rbq = (size_t)y * WW;
        f2 i0 = *(const f2*)(Ib + rbq + gc);
        f2 i1 = *(const f2*)(Ib + (size_t)HH * WW + rbq + gc);
        f2 i2 = *(const f2*)(Ib + (size_t)2 * HH * WW + rbq + gc);
        if (upd) {
            int ra = refl(y + 1 + RR, HH);
            int rs = refl(y - RR, HH);
            size_t rba = (size_t)ra * WW;
            size_t rbs = (size_t)rs * WW;
            aa0 = __builtin_convertvector(*(const h2*)(A0p + rba + gc), f2);
            aa1 = __builtin_convertvector(*(const h2*)(A1p + rba + gc), f2);
            aa2 = __builtin_convertvector(*(const h2*)(A2p + rba + gc), f2);
            ab  = __builtin_convertvector(*(const h2*)(Bp + rba + gc), f2);
            sa0 = __builtin_convertvector(*(const h2*)(A0p + rbs + gc), f2);
            sa1 = __builtin_convertvector(*(const h2*)(A1p + rbs + gc), f2);
            sa2 = __builtin_convertvector(*(const h2*)(A2p + rbs + gc), f2);
            sb  = __builtin_convertvector(*(const h2*)(Bp + rbs + gc), f2);
            if (isHalo) {
                ha0 = (float)A0p[rba + hg]; ha1 = (float)A1p[rba + hg];
                ha2 = (float)A2p[rba + hg]; hab = (float)Bp[rba + hg];
                hb0 = (float)A0p[rbs + hg]; hb1 = (float)A1p[rbs + hg];
                hb2 = (float)A2p[rbs + hg]; hbb = (float)Bp[rbs + hg];
            }
        }
        __syncthreads();

        f2 m[NCH2];
        #pragma unroll
        for (int ch = 0; ch < NCH2; ++ch)
            m[ch] = hwin2(&lds[ch][0], c0);

        f2 qv = m[0] * i0 + m[1] * i1 + m[2] * i2 + m[3];
        *(f2*)(Q + (size_t)bz * HH * WW + rbq + gc) = qv;
        __syncthreads();

        if (upd) {
            vs[0] += aa0 - sa0;
            vs[1] += aa1 - sa1;
            vs[2] += aa2 - sa2;
            vs[3] += ab - sb;
            if (isHalo) {
                hs[0] += ha0 - hb0; hs[1] += ha1 - hb1;
                hs[2] += ha2 - hb2; hs[3] += hab - hbb;
            }
        }
    }
}

extern "C" void kernel_launch(void* const* d_in, const int* in_sizes, int n_in,
                              void* d_out, int out_size, void* d_ws, size_t ws_size,
                              hipStream_t stream) {
    const float* I = (const float*)d_in[0];
    const float* P = (const float*)d_in[1];
    float* Q = (float*)d_out;
    _Float16* A = (_Float16*)d_ws;                       // B*3*H*W halves
    _Float16* Bc = A + (size_t)NB * 3 * HH * WW;         // B*H*W halves
    gf_stage1<<<NBLK1, 256, 0, stream>>>(I, P, A, Bc);
    gf_stage2<<<NBLK2, 256, 0, stream>>>(I, A, Bc, Q);
}